// Round 8
// baseline (54.994 us; speedup 1.0000x reference)
//
#include <hip/hip_runtime.h>
#include <stdint.h>

constexpr int Dz = 96, Hy = 160, Wx = 160;
constexpr int NVOX = Dz * Hy * Wx;

// Stage-1 footprint of a 32d x 32w x 2h block (x=53d/32, z=19w/32, y=159h/160)
constexpr int ZSPAN = 20, YSPAN = 3, XSPAN = 53;   // unpadded, i-linear LDS layout
constexpr int NL = ZSPAN * YSPAN * XSPAN;          // 3180 floats per plane
constexpr int NSLOT = (NL + 255) / 256;            // 13 load slots per thread (= 13 vmcnt ticks/wave/plane)
constexpr int LBUF = NSLOT * 256;                  // 3328 floats per buffer (tail junk ok)

typedef __attribute__((address_space(3))) float lds_f;
typedef __attribute__((address_space(1))) const void gbl_v;

// Counted-vmcnt barrier: retire the oldest loads only; keep deeper prefetch in flight
// ACROSS the barrier (T3/T4). "memory" clobber orders the subsequent ds_reads.
#define PLANE_SYNC(N)                                          \
    asm volatile("s_waitcnt vmcnt(" #N ")" ::: "memory");      \
    __builtin_amdgcn_s_barrier();                              \
    __builtin_amdgcn_sched_barrier(0)

__global__ __launch_bounds__(256) void st_fused_kernel(
    const float* __restrict__ src,
    const float* __restrict__ flows,
    const float* __restrict__ rfp,
    float* __restrict__ out)
{
    __shared__ float raw[4][LBUF];   // 53248 B quad buffer (depth-3 prefetch)
    const int t = threadIdx.x;

    // XCD-aware bijective swizzle: 1200 blocks = 8 XCDs x 150
    const int bid = blockIdx.x;
    const int swz = (bid & 7) * 150 + (bid >> 3);
    const int bx = swz % 5;
    const int rest = swz / 5;
    const int by = rest % 3;
    const int bz = rest / 3;
    const int w0 = bx * 32, d0 = by * 32, h0 = bz * 2;
    const float rf = *rfp;

    const int Z0 = (19 * w0) >> 5;
    const int X0 = (53 * d0) >> 5;
    const int YB = (159 * h0) / 160;

    // ---- 13 live 64-bit load addresses, incremented by plane stride ----
    const char* ap[NSLOT];
    {
        const char* fb = (const char*)flows + ((size_t)(Z0 * Hy + YB) * Wx + X0) * 4;
#pragma unroll
        for (int u = 0; u < NSLOT; ++u) {
            int i = t + u * 256;
            int ic = i < NL ? i : NL - 1;      // tail lanes: clamped dup loads (LDS junk, never read)
            int r = ic / XSPAN;
            int x = ic - r * XSPAN;
            int z = r / YSPAN;
            int y = r - z * YSPAN;
            ap[u] = fb + ((z * Hy + y) * Wx + x) * 4;
        }
    }

    auto issue_loads = [&](float* lb) {
#pragma unroll
        for (int u = 0; u < NSLOT; ++u) {
            __builtin_amdgcn_global_load_lds(
                (gbl_v*)ap[u], (lds_f*)&lb[t + u * 256], 4, 0, 0);
        }
#pragma unroll
        for (int u = 0; u < NSLOT; ++u) ap[u] += (size_t)NVOX * 4;
    };

    // ---- compute-phase constants: lanes vary w (stage-1 z axis) ----
    const int wl = t & 31;
    const int w = w0 + wl;
    const float zf = (float)(19 * w) * (1.0f / 32.0f);
    const int z0i = (int)zf;
    const float fz = zf - (float)z0i;
    const int zz = z0i - Z0;                    // 0..18
    const float wz0 = 1.0f - fz, wz1 = fz;

    const int dbase = t >> 5;                   // 0..7
    int xx[4]; float wx0[4], wx1[4];
#pragma unroll
    for (int k = 0; k < 4; ++k) {
        const int d = d0 + dbase + 8 * k;
        const float xf = (float)(53 * d) * (1.0f / 32.0f);
        const int x0i = (int)xf;
        const float fx = xf - (float)x0i;
        xx[k] = x0i - X0;                       // 0..51
        wx0[k] = 1.0f - fx; wx1[k] = fx;
    }

    float wyr[2][3];
#pragma unroll
    for (int j = 0; j < 2; ++j) {
        const int h = h0 + j;
        const float yf = (float)h * (159.0f / 160.0f);
        const int y0i = (int)yf;
        const float fy = yf - (float)y0i;
        const int yrel = y0i - YB;              // 0 or 1
        const float a = 1.0f - fy, b = fy;
        wyr[j][0] = (yrel == 0) ? a : 0.0f;
        wyr[j][1] = (yrel == 0) ? b : a;
        wyr[j][2] = (yrel == 0) ? 0.0f : b;
    }

    auto compute = [&](const float* lb, float (&v)[4][2]) {
        const float* zrow = lb + zz * (YSPAN * XSPAN);   // stride 159 ≡ -1 (mod 32): conflict-free
#pragma unroll
        for (int k = 0; k < 4; ++k) {
            float zv0[3], zv1[3];
#pragma unroll
            for (int yy = 0; yy < 3; ++yy) {
                const float* r0 = zrow + yy * XSPAN + xx[k];
                const float a0 = r0[0], a1 = r0[1];
                const float b0 = r0[YSPAN * XSPAN], b1 = r0[YSPAN * XSPAN + 1];
                zv0[yy] = wz0 * a0 + wz1 * b0;
                zv1[yy] = wz0 * a1 + wz1 * b1;
            }
#pragma unroll
            for (int j = 0; j < 2; ++j) {
                const float yv0 = wyr[j][0] * zv0[0] + wyr[j][1] * zv0[1] + wyr[j][2] * zv0[2];
                const float yv1 = wyr[j][0] * zv1[0] + wyr[j][1] * zv1[1] + wyr[j][2] * zv1[2];
                v[k][j] = wx0[k] * yv0 + wx1[k] * yv1;
            }
        }
    };

    float accA[4][2], accB[4][2], accC[4][2];
#pragma unroll
    for (int k = 0; k < 4; ++k)
#pragma unroll
        for (int j = 0; j < 2; ++j) { accA[k][j] = 0.f; accB[k][j] = 0.f; accC[k][j] = 0.f; }

#define ACC_ADD(ACC) do { float v[4][2]; compute(q0, v); \
    _Pragma("unroll") \
    for (int k = 0; k < 4; ++k) { ACC[k][0] += v[k][0]; ACC[k][1] += v[k][1]; } } while (0)
#define ROT4() do { float* tmp = q0; q0 = q1; q1 = q2; q2 = q3; q3 = tmp; } while (0)

    // ---- deep pipeline: quad buffer, counted vmcnt, 1 raw barrier/plane ----
    // Invariant at plane p: q0..q3 = buffers of planes p..p+3; plane p+3's target
    // buffer was last read at plane p-1, and the barrier proves all waves are done with it.
    issue_loads(&raw[0][0]);   // plane 0
    issue_loads(&raw[1][0]);   // plane 1
    issue_loads(&raw[2][0]);   // plane 2
    float* q0 = &raw[0][0];
    float* q1 = &raw[1][0];
    float* q2 = &raw[2][0];
    float* q3 = &raw[3][0];

#pragma unroll 1
    for (int i = 0; i < 2; ++i) {           // planes 0..5
        PLANE_SYNC(26);                     // plane 3i+0 landed; 2 planes stay in flight
        issue_loads(q3);                    // plane 3i+3
        ACC_ADD(accA);
        ROT4();

        PLANE_SYNC(26);                     // plane 3i+1
        issue_loads(q3);                    // plane 3i+4
        ACC_ADD(accB);
        ROT4();

        PLANE_SYNC(26);                     // plane 3i+2
        issue_loads(q3);                    // plane 3i+5
        ACC_ADD(accC);
        ROT4();
    }
    PLANE_SYNC(26);                         // plane 6
    ACC_ADD(accA);
    ROT4();
    PLANE_SYNC(13);                         // plane 7
    ACC_ADD(accB);
    ROT4();
    PLANE_SYNC(0);                          // plane 8
    ACC_ADD(accC);

#undef ACC_ADD
#undef ROT4

    // ---- stage 2: sample src (zeros mode), lanes vary w -> coalesced store ----
#pragma unroll
    for (int j = 0; j < 2; ++j) {
        const int h = h0 + j;
#pragma unroll
        for (int k = 0; k < 4; ++k) {
            const int d = d0 + dbase + 8 * k;
            const float f0 = (float)d + accA[k][j] * rf;   // -> x axis of src
            const float f1 = (float)h + accB[k][j] * rf;   // -> y axis
            const float f2 = (float)w + accC[k][j] * rf;   // -> z axis

            const float xs = f0 * (159.0f / 95.0f);
            const float ys = f1;
            const float zs = f2 * (95.0f / 159.0f);

            const float xs0f = floorf(xs), ys0f = floorf(ys), zs0f = floorf(zs);
            const float gx = xs - xs0f, gy = ys - ys0f, gz = zs - zs0f;
            const int xi0 = (int)xs0f, yi0 = (int)ys0f, zi0 = (int)zs0f;
            const int xi1 = xi0 + 1, yi1 = yi0 + 1, zi1 = zi0 + 1;

            auto samp = [&](int zi, int yi, int xi, float wt) -> float {
                bool valid = ((unsigned)zi < (unsigned)Dz)
                           & ((unsigned)yi < (unsigned)Hy)
                           & ((unsigned)xi < (unsigned)Wx);
                int zc = min(max(zi, 0), Dz - 1);
                int yc = min(max(yi, 0), Hy - 1);
                int xc = min(max(xi, 0), Wx - 1);
                float v = src[(zc * Hy + yc) * Wx + xc];
                return valid ? wt * v : 0.0f;
            };

            float r = samp(zi0, yi0, xi0, (1.0f - gz) * (1.0f - gy) * (1.0f - gx))
                    + samp(zi0, yi0, xi1, (1.0f - gz) * (1.0f - gy) * gx)
                    + samp(zi0, yi1, xi0, (1.0f - gz) * gy * (1.0f - gx))
                    + samp(zi0, yi1, xi1, (1.0f - gz) * gy * gx)
                    + samp(zi1, yi0, xi0, gz * (1.0f - gy) * (1.0f - gx))
                    + samp(zi1, yi0, xi1, gz * (1.0f - gy) * gx)
                    + samp(zi1, yi1, xi0, gz * gy * (1.0f - gx))
                    + samp(zi1, yi1, xi1, gz * gy * gx);

            out[(d * Hy + h) * Wx + w] = r;
        }
    }
}

extern "C" void kernel_launch(void* const* d_in, const int* in_sizes, int n_in,
                              void* d_out, int out_size, void* d_ws, size_t ws_size,
                              hipStream_t stream) {
    const float* src   = (const float*)d_in[0];
    const float* flows = (const float*)d_in[1];
    const float* rfp   = (const float*)d_in[2];
    float* out = (float*)d_out;

    st_fused_kernel<<<dim3(1200), 256, 0, stream>>>(src, flows, rfp, out);
}

// Round 9
// 45.129 us; speedup vs baseline: 1.2186x; 1.2186x over previous
//
#include <hip/hip_runtime.h>
#include <stdint.h>

constexpr int Dz = 96, Hy = 160, Wx = 160;
constexpr int NVOX = Dz * Hy * Wx;

// Stage-1 footprint of a 32d x 32w x 2h block (x=53d/32, z=19w/32, y=159h/160)
constexpr int ZSPAN = 20, YSPAN = 3, XSPAN = 53;   // unpadded, i-linear LDS layout
constexpr int NL = ZSPAN * YSPAN * XSPAN;          // 3180 floats per plane
constexpr int NSLOT = (NL + 255) / 256;            // 13 load slots per thread (= vmcnt ticks/wave/plane)
constexpr int LBUF = NSLOT * 256;                  // 3328 floats per buffer (tail junk ok)

typedef __attribute__((address_space(3))) float lds_f;
typedef __attribute__((address_space(1))) const void gbl_v;

// Counted-vmcnt barrier: retire the oldest loads only; keep deeper prefetch in flight.
#define PLANE_SYNC(N)                                          \
    asm volatile("s_waitcnt vmcnt(" #N ")" ::: "memory");      \
    __builtin_amdgcn_s_barrier();                              \
    __builtin_amdgcn_sched_barrier(0)

__global__ __launch_bounds__(256) void st_fused_kernel(
    const float* __restrict__ src,
    const float* __restrict__ flows,
    const float* __restrict__ rfp,
    float* __restrict__ out)
{
    __shared__ float raw[4][LBUF];   // 53248 B quad buffer; reused for output transpose
    const int t = threadIdx.x;

    // XCD-aware bijective swizzle: 1200 blocks = 8 XCDs x 150
    const int bid = blockIdx.x;
    const int swz = (bid & 7) * 150 + (bid >> 3);
    const int bx = swz % 5;
    const int rest = swz / 5;
    const int by = rest % 3;
    const int bz = rest / 3;
    const int w0 = bx * 32, d0 = by * 32, h0 = bz * 2;
    const float rf = *rfp;

    const int Z0 = (19 * w0) >> 5;
    const int X0 = (53 * d0) >> 5;
    const int YB = (159 * h0) / 160;

    // ---- 13 live 64-bit load addresses, incremented by plane stride ----
    const char* ap[NSLOT];
    {
        const char* fb = (const char*)flows + ((size_t)(Z0 * Hy + YB) * Wx + X0) * 4;
#pragma unroll
        for (int u = 0; u < NSLOT; ++u) {
            int i = t + u * 256;
            int ic = i < NL ? i : NL - 1;      // tail lanes: clamped dup loads (LDS junk, never read)
            int r = ic / XSPAN;
            int x = ic - r * XSPAN;
            int z = r / YSPAN;
            int y = r - z * YSPAN;
            ap[u] = fb + ((z * Hy + y) * Wx + x) * 4;
        }
    }

    auto issue_loads = [&](float* lb) {
#pragma unroll
        for (int u = 0; u < NSLOT; ++u) {
            __builtin_amdgcn_global_load_lds(
                (gbl_v*)ap[u], (lds_f*)&lb[t + u * 256], 4, 0, 0);
        }
#pragma unroll
        for (int u = 0; u < NSLOT; ++u) ap[u] += (size_t)NVOX * 4;
    };

    // ---- compute-phase mapping: lanes vary d (stage-2 x axis = stride 1) ----
    const int dl = t & 31;                      // lane: d
    const int wg = t >> 5;                      // thread-group: w base
    const int d  = d0 + dl;

    // per-lane x interp (stage-1)
    const float xf = (float)(53 * d) * (1.0f / 32.0f);
    const int   x0i = (int)xf;
    const float fx  = xf - (float)x0i;
    const int   xx  = x0i - X0;                 // 0..51
    const float wxa = 1.0f - fx, wxb = fx;

    // per-k z interp (stage-1): w = w0 + wg + 8k
    int zzk[4]; float wz0[4], wz1[4];
#pragma unroll
    for (int k = 0; k < 4; ++k) {
        const int w = w0 + wg + 8 * k;
        const float zf = (float)(19 * w) * (1.0f / 32.0f);
        const int z0i = (int)zf;
        const float fz = zf - (float)z0i;
        zzk[k] = z0i - Z0;                      // 0..18
        wz0[k] = 1.0f - fz; wz1[k] = fz;
    }

    float wyr[2][3];
#pragma unroll
    for (int j = 0; j < 2; ++j) {
        const int h = h0 + j;
        const float yf = (float)h * (159.0f / 160.0f);
        const int y0i = (int)yf;
        const float fy = yf - (float)y0i;
        const int yrel = y0i - YB;              // 0 or 1
        const float a = 1.0f - fy, b = fy;
        wyr[j][0] = (yrel == 0) ? a : 0.0f;
        wyr[j][1] = (yrel == 0) ? b : a;
        wyr[j][2] = (yrel == 0) ? 0.0f : b;
    }

    auto compute = [&](const float* lb, float (&v)[4][2]) {
#pragma unroll
        for (int k = 0; k < 4; ++k) {
            const float* base = lb + zzk[k] * (YSPAN * XSPAN) + xx;
            float zv[3];
#pragma unroll
            for (int yy = 0; yy < 3; ++yy) {
                const float* r0 = base + yy * XSPAN;
                const float a0 = r0[0], a1 = r0[1];                          // z0 row
                const float b0 = r0[YSPAN * XSPAN], b1 = r0[YSPAN * XSPAN + 1]; // z1 row
                const float xv0 = wxa * a0 + wxb * a1;
                const float xv1 = wxa * b0 + wxb * b1;
                zv[yy] = wz0[k] * xv0 + wz1[k] * xv1;
            }
#pragma unroll
            for (int j = 0; j < 2; ++j)
                v[k][j] = wyr[j][0] * zv[0] + wyr[j][1] * zv[1] + wyr[j][2] * zv[2];
        }
    };

    float accA[4][2], accB[4][2], accC[4][2];
#pragma unroll
    for (int k = 0; k < 4; ++k)
#pragma unroll
        for (int j = 0; j < 2; ++j) { accA[k][j] = 0.f; accB[k][j] = 0.f; accC[k][j] = 0.f; }

#define ACC_ADD(ACC) do { float v[4][2]; compute(q0, v); \
    _Pragma("unroll") \
    for (int k = 0; k < 4; ++k) { ACC[k][0] += v[k][0]; ACC[k][1] += v[k][1]; } } while (0)
#define ROT4() do { float* tmp = q0; q0 = q1; q1 = q2; q2 = q3; q3 = tmp; } while (0)

    // ---- deep pipeline: quad buffer, counted vmcnt, 1 raw barrier/plane ----
    issue_loads(&raw[0][0]);   // plane 0
    issue_loads(&raw[1][0]);   // plane 1
    issue_loads(&raw[2][0]);   // plane 2
    float* q0 = &raw[0][0];
    float* q1 = &raw[1][0];
    float* q2 = &raw[2][0];
    float* q3 = &raw[3][0];

#pragma unroll 1
    for (int i = 0; i < 2; ++i) {           // planes 0..5
        PLANE_SYNC(26);                     // plane 3i+0 landed; 2 planes stay in flight
        issue_loads(q3);                    // plane 3i+3
        ACC_ADD(accA);
        ROT4();

        PLANE_SYNC(26);                     // plane 3i+1
        issue_loads(q3);                    // plane 3i+4
        ACC_ADD(accB);
        ROT4();

        PLANE_SYNC(26);                     // plane 3i+2
        issue_loads(q3);                    // plane 3i+5
        ACC_ADD(accC);
        ROT4();
    }
    PLANE_SYNC(26);                         // plane 6
    ACC_ADD(accA);
    ROT4();
    PLANE_SYNC(13);                         // plane 7
    ACC_ADD(accB);
    ROT4();
    PLANE_SYNC(0);                          // plane 8
    ACC_ADD(accC);

#undef ACC_ADD
#undef ROT4

    // ---- stage 2: sample src (zeros mode); per-lane d -> x-axis coalesced gathers ----
    float res[4][2];
#pragma unroll
    for (int j = 0; j < 2; ++j) {
        const int h = h0 + j;
#pragma unroll
        for (int k = 0; k < 4; ++k) {
            const int w = w0 + wg + 8 * k;
            const float f0 = (float)d + accA[k][j] * rf;   // -> x axis of src
            const float f1 = (float)h + accB[k][j] * rf;   // -> y axis
            const float f2 = (float)w + accC[k][j] * rf;   // -> z axis

            const float xs = f0 * (159.0f / 95.0f);
            const float ys = f1;
            const float zs = f2 * (95.0f / 159.0f);

            const float xs0f = floorf(xs), ys0f = floorf(ys), zs0f = floorf(zs);
            const float gx = xs - xs0f, gy = ys - ys0f, gz = zs - zs0f;
            const int xi0 = (int)xs0f, yi0 = (int)ys0f, zi0 = (int)zs0f;
            const int xi1 = xi0 + 1, yi1 = yi0 + 1, zi1 = zi0 + 1;

            auto samp = [&](int zi, int yi, int xi, float wt) -> float {
                bool valid = ((unsigned)zi < (unsigned)Dz)
                           & ((unsigned)yi < (unsigned)Hy)
                           & ((unsigned)xi < (unsigned)Wx);
                int zc = min(max(zi, 0), Dz - 1);
                int yc = min(max(yi, 0), Hy - 1);
                int xc = min(max(xi, 0), Wx - 1);
                float v = src[(zc * Hy + yc) * Wx + xc];
                return valid ? wt * v : 0.0f;
            };

            res[k][j] = samp(zi0, yi0, xi0, (1.0f - gz) * (1.0f - gy) * (1.0f - gx))
                      + samp(zi0, yi0, xi1, (1.0f - gz) * (1.0f - gy) * gx)
                      + samp(zi0, yi1, xi0, (1.0f - gz) * gy * (1.0f - gx))
                      + samp(zi0, yi1, xi1, (1.0f - gz) * gy * gx)
                      + samp(zi1, yi0, xi0, gz * (1.0f - gy) * (1.0f - gx))
                      + samp(zi1, yi0, xi1, gz * (1.0f - gy) * gx)
                      + samp(zi1, yi1, xi0, gz * gy * (1.0f - gx))
                      + samp(zi1, yi1, xi1, gz * gy * gx);
        }
    }

    // ---- output transpose in LDS (reuse raw; rows padded +1 -> conflict-free) ----
    __syncthreads();                            // all waves done reading plane buffers
    float* tr = &raw[0][0];                     // [2][32][33] floats = 8448 B
#pragma unroll
    for (int j = 0; j < 2; ++j)
#pragma unroll
        for (int k = 0; k < 4; ++k)
            tr[(j * 32 + dl) * 33 + (wg + 8 * k)] = res[k][j];
    __syncthreads();

    const int wl = t & 31;
    const int rg = t >> 5;
#pragma unroll
    for (int j = 0; j < 2; ++j)
#pragma unroll
        for (int m = 0; m < 4; ++m) {
            const int dr = rg + 8 * m;
            out[((size_t)(d0 + dr) * Hy + (h0 + j)) * Wx + (w0 + wl)] =
                tr[(j * 32 + dr) * 33 + wl];
        }
}

extern "C" void kernel_launch(void* const* d_in, const int* in_sizes, int n_in,
                              void* d_out, int out_size, void* d_ws, size_t ws_size,
                              hipStream_t stream) {
    const float* src   = (const float*)d_in[0];
    const float* flows = (const float*)d_in[1];
    const float* rfp   = (const float*)d_in[2];
    float* out = (float*)d_out;

    st_fused_kernel<<<dim3(1200), 256, 0, stream>>>(src, flows, rfp, out);
}